// Round 3
// baseline (610.415 us; speedup 1.0000x reference)
//
#include <hip/hip_runtime.h>
#include <hip/hip_bf16.h>

#define T_TOK 8192
#define DMODEL 1024
#define DFF 4096
#define NEXP 8
#define CAP 1024

typedef __attribute__((ext_vector_type(8))) __bf16 bf16x8;
typedef __attribute__((ext_vector_type(4))) float f32x4;

__device__ __forceinline__ unsigned short f2bf(float f) {
  union { float f; unsigned int u; } v;
  v.f = f;
  return (unsigned short)((v.u + 0x7fffu + ((v.u >> 16) & 1u)) >> 16);
}

// A&S 7.1.26 erf (|err| <= 1.5e-7), fast exp/rcp. gelu = 0.5 v (1+erf(v/sqrt2))
__device__ __forceinline__ float fast_gelu(float v) {
  float x = fabsf(v) * 0.70710678118654752440f;
  float t = __builtin_amdgcn_rcpf(1.0f + 0.3275911f * x);
  float poly = t * (0.254829592f + t * (-0.284496736f + t * (1.421413741f +
               t * (-1.453152027f + t * 1.061405429f))));
  float er = 1.0f - poly * __expf(-x * x);
  float s = (v >= 0.0f) ? er : -er;
  return 0.5f * v * (1.0f + s);
}

__device__ __forceinline__ void load_lds16(const unsigned short* g, unsigned short* l) {
  __builtin_amdgcn_global_load_lds((const __attribute__((address_space(1))) void*)g,
                                   (__attribute__((address_space(3))) void*)l,
                                   16, 0, 0);
}

// ---------------- router (fused x fp32->bf16 convert): one wave per token ----------------
__global__ void k_router(const float* __restrict__ x, const float* __restrict__ rw,
                         unsigned short* __restrict__ xb,
                         int* __restrict__ tk_idx, float* __restrict__ tk_w) {
  int wv = threadIdx.x >> 6, lane = threadIdx.x & 63;
  int t = blockIdx.x * 4 + wv;
  const float4* xr = (const float4*)(x + (size_t)t * DMODEL);
  uint2* xbw = (uint2*)(xb + (size_t)t * DMODEL);
  float acc[NEXP];
#pragma unroll
  for (int e = 0; e < NEXP; ++e) acc[e] = 0.f;
#pragma unroll
  for (int j = 0; j < DMODEL / 256; ++j) {
    float4 v = xr[j * 64 + lane];
#pragma unroll
    for (int e = 0; e < NEXP; ++e) {
      float4 w = ((const float4*)(rw + e * DMODEL))[j * 64 + lane];
      acc[e] += v.x * w.x + v.y * w.y + v.z * w.z + v.w * w.w;
    }
    uint2 p;
    p.x = (unsigned int)f2bf(v.x) | ((unsigned int)f2bf(v.y) << 16);
    p.y = (unsigned int)f2bf(v.z) | ((unsigned int)f2bf(v.w) << 16);
    xbw[j * 64 + lane] = p;
  }
#pragma unroll
  for (int e = 0; e < NEXP; ++e)
    for (int off = 32; off; off >>= 1) acc[e] += __shfl_xor(acc[e], off);
  if (lane == 0) {
    int i0 = 0;
    for (int e = 1; e < NEXP; ++e) if (acc[e] > acc[i0]) i0 = e;
    int i1 = (i0 == 0) ? 1 : 0;
    for (int e = 0; e < NEXP; ++e) if (e != i0 && acc[e] > acc[i1]) i1 = e;
    float ex = expf(acc[i1] - acc[i0]);  // <= 1
    float w0 = 1.f / (1.f + ex);
    float w1 = ex / (1.f + ex);
    tk_idx[2 * t] = i0; tk_idx[2 * t + 1] = i1;
    tk_w[2 * t] = w0;  tk_w[2 * t + 1] = w1;
  }
}

// ---------------- fp32 [E][Kd][Nd] -> bf16 [E][Nd][Kd] ----------------
__global__ void k_transpose_cvt(const float* __restrict__ src, unsigned short* __restrict__ dst,
                                int Kd, int Nd) {
  __shared__ unsigned short tile[64][73];
  int e = blockIdx.z;
  size_t k0 = (size_t)blockIdx.y * 64, n0 = (size_t)blockIdx.x * 64;
  int tid = threadIdx.x;
  const float* sb = src + (size_t)e * Kd * Nd;
  int r = tid >> 4, cg = (tid & 15) * 4;
  for (int rr = 0; rr < 4; ++rr) {
    int row = r + rr * 16;
    float4 v = *(const float4*)(sb + (k0 + row) * Nd + n0 + cg);
    tile[row][cg + 0] = f2bf(v.x);
    tile[row][cg + 1] = f2bf(v.y);
    tile[row][cg + 2] = f2bf(v.z);
    tile[row][cg + 3] = f2bf(v.w);
  }
  __syncthreads();
  unsigned short* db = dst + (size_t)e * Nd * Kd;
  int rn = tid >> 3, kg = (tid & 7) * 8;
  for (int rr = 0; rr < 2; ++rr) {
    int nrow = rn + rr * 32;
    union { unsigned short h[8]; uint4 v; } o;
#pragma unroll
    for (int j = 0; j < 8; ++j) o.h[j] = tile[kg + j][nrow];
    *(uint4*)(db + (n0 + nrow) * Kd + k0 + kg) = o.v;
  }
}

// ---------------- capacity scan / dispatch (single block, in token order) ----------------
__global__ void k_scan(const int* __restrict__ tk_idx, const float* __restrict__ tk_w,
                       int* __restrict__ etok, float* __restrict__ egate,
                       float* __restrict__ loss_out) {
  __shared__ int wavecnt[16][NEXP];
  __shared__ int waveoff[16][NEXP];
  __shared__ int offs[NEXP];
  __shared__ int ctot[NEXP];
  int tid = threadIdx.x;
  int lane = tid & 63, wv = tid >> 6;
  if (tid < NEXP) offs[tid] = 0;
  for (int i = tid; i < NEXP * CAP; i += 1024) { etok[i] = 0; egate[i] = 0.f; }
  __syncthreads();
  unsigned long long lt = (1ULL << lane) - 1ULL;
  for (int c = 0; c < T_TOK / 1024; ++c) {
    int t = c * 1024 + tid;
    int e0 = tk_idx[2 * t], e1 = tk_idx[2 * t + 1];
    float w0 = tk_w[2 * t], w1 = tk_w[2 * t + 1];
    int p0 = 0, p1 = 0;
#pragma unroll
    for (int e = 0; e < NEXP; ++e) {
      unsigned long long bal = __ballot((e0 == e) || (e1 == e));
      if (e0 == e) p0 = __popcll(bal & lt);
      if (e1 == e) p1 = __popcll(bal & lt);
      if (lane == 0) wavecnt[wv][e] = __popcll(bal);
    }
    __syncthreads();
    if (tid < NEXP) {
      int s = 0;
      for (int w = 0; w < 16; ++w) { waveoff[w][tid] = s; s += wavecnt[w][tid]; }
      ctot[tid] = s;
    }
    __syncthreads();
    int r0 = offs[e0] + waveoff[wv][e0] + p0;
    int r1 = offs[e1] + waveoff[wv][e1] + p1;
    if (r0 < CAP) { etok[e0 * CAP + r0] = t; egate[e0 * CAP + r0] = w0; }
    if (r1 < CAP) { etok[e1 * CAP + r1] = t; egate[e1 * CAP + r1] = w1; }
    __syncthreads();
    if (tid < NEXP) offs[tid] += ctot[tid];
    __syncthreads();
  }
  if (tid == 0) {
    float loss = 0.f;
    for (int e = 0; e < NEXP; ++e) {
      float d = (float)offs[e] - 2048.0f;
      loss += d * d;
    }
    loss_out[0] = loss / (8192.0f * 8192.0f);
  }
}

// ---------------- GEMM1: H[e] = gelu(X[etok[e]] @ w1[e] + b1[e]) -> bf16 ----------------
// Swapped-operand MFMA (acc holds D^T: lane = 1 token row x 4 contiguous ff cols).
// Epilogue reuses the 16 KB k-loop LDS (per-wave 64x16-col rounds, stride 24 shorts)
// so LDS stays 16 KB -> ~6 blocks/CU instead of 4.
__global__ __launch_bounds__(256) void k_gemm1(
    const unsigned short* __restrict__ xb, const unsigned short* __restrict__ w1t,
    const float* __restrict__ b1, const int* __restrict__ etok,
    unsigned short* __restrict__ H) {
  __shared__ __align__(16) unsigned short smem[8192];  // As[0..4096) Bs[4096..8192); epilogue reuse
  unsigned short* As = smem;
  unsigned short* Bs = smem + 4096;
  int tid = threadIdx.x;
  int lane = tid & 63, wv = tid >> 6;
  int bid = blockIdx.x;
  int e = bid >> 8;
  int b = bid & 255;
  // swizzle: same n-tile => same (bid mod 8) => same XCD => B fetched once per L2
  int nl = b & 7, m = (b >> 3) & 7, nh = b >> 6;
  int m0 = m * 128, n0 = (nh * 8 + nl) * 128;

  const unsigned short* gA[2];
  const unsigned short* gB[2];
  unsigned short* lA[2];
  unsigned short* lB[2];
#pragma unroll
  for (int s = 0; s < 2; ++s) {
    int i = s * 256 + tid;
    int row = i >> 2, cb = (i & 3) * 8;
    int tok = etok[e * CAP + m0 + row];
    gA[s] = xb + (size_t)tok * DMODEL + cb;
    gB[s] = w1t + ((size_t)e * DFF + n0 + row) * DMODEL + cb;
    int wb = (s * 256 + wv * 64) * 8;
    lA[s] = As + wb;
    lB[s] = Bs + wb;
  }

  f32x4 zero = {0.f, 0.f, 0.f, 0.f};
  f32x4 acc[4][4];
#pragma unroll
  for (int mi = 0; mi < 4; ++mi)
#pragma unroll
    for (int ni = 0; ni < 4; ++ni) acc[mi][ni] = zero;

  int wm = (wv >> 1) * 64, wn = (wv & 1) * 64;
  int fr = lane & 15, quad = lane >> 4;
  const unsigned short* pa = As + (wm + fr) * 32 + quad * 8;
  const unsigned short* pb = Bs + (wn + fr) * 32 + quad * 8;

  for (int k0 = 0; k0 < DMODEL; k0 += 32) {
#pragma unroll
    for (int s = 0; s < 2; ++s) {
      load_lds16(gA[s] + k0, lA[s]);
      load_lds16(gB[s] + k0, lB[s]);
    }
    __syncthreads();
    bf16x8 av[4], bv[4];
#pragma unroll
    for (int mi = 0; mi < 4; ++mi) av[mi] = *(const bf16x8*)(pa + mi * 16 * 32);
#pragma unroll
    for (int ni = 0; ni < 4; ++ni) bv[ni] = *(const bf16x8*)(pb + ni * 16 * 32);
#pragma unroll
    for (int mi = 0; mi < 4; ++mi)
#pragma unroll
      for (int ni = 0; ni < 4; ++ni)
        acc[mi][ni] = __builtin_amdgcn_mfma_f32_16x16x32_bf16(bv[ni], av[mi], acc[mi][ni], 0, 0, 0);
    __syncthreads();
  }

  // epilogue: acc[mi][ni][rr] = val(token m0+wm+mi*16+fr, ff col n0+wn+ni*16+quad*4+rr)
  // per-wave region: 64 rows x 16 cols per round, LDS stride 24 shorts (48 B, 16B-aligned)
  unsigned short* EP = smem + wv * 1536;
#pragma unroll
  for (int ni = 0; ni < 4; ++ni) {
    float4 b4 = *(const float4*)(b1 + e * DFF + n0 + wn + ni * 16 + quad * 4);
#pragma unroll
    for (int mi = 0; mi < 4; ++mi) {
      float v0 = fast_gelu(acc[mi][ni][0] + b4.x);
      float v1 = fast_gelu(acc[mi][ni][1] + b4.y);
      float v2 = fast_gelu(acc[mi][ni][2] + b4.z);
      float v3 = fast_gelu(acc[mi][ni][3] + b4.w);
      uint2 p;
      p.x = (unsigned int)f2bf(v0) | ((unsigned int)f2bf(v1) << 16);
      p.y = (unsigned int)f2bf(v2) | ((unsigned int)f2bf(v3) << 16);
      *(uint2*)(EP + (mi * 16 + fr) * 24 + quad * 4) = p;
    }
#pragma unroll
    for (int t = 0; t < 2; ++t) {
      int row = t * 32 + (lane >> 1), chunk = lane & 1;
      uint4 v = *(const uint4*)(EP + row * 24 + chunk * 8);
      *(uint4*)(H + ((size_t)e * CAP + m0 + wm + row) * DFF + n0 + wn + ni * 16 + chunk * 8) = v;
    }
  }
}

// ---------------- GEMM2 (split-K=2): out[tok] += gate * (H[e] @ w2[e] [+ b2[e] on slice 0]) ----
__global__ __launch_bounds__(256) void k_gemm2(
    const unsigned short* __restrict__ H, const unsigned short* __restrict__ w2t,
    const float* __restrict__ b2, const int* __restrict__ etok,
    const float* __restrict__ egate, float* __restrict__ out) {
  __shared__ __align__(16) unsigned short smem[8192];
  unsigned short* As = smem;
  unsigned short* Bs = smem + 4096;
  int tid = threadIdx.x;
  int lane = tid & 63, wv = tid >> 6;
  int bid = blockIdx.x;
  int e = bid >> 7;
  int ks = (bid >> 6) & 1;           // k-slice
  int m0 = ((bid >> 3) & 7) * 128;
  int n0 = (bid & 7) * 128;          // bid%8 = n-tile => same XCD shares B
  int kbase = ks * (DFF / 2);

  const unsigned short* gA[2];
  const unsigned short* gB[2];
  unsigned short* lA[2];
  unsigned short* lB[2];
#pragma unroll
  for (int s = 0; s < 2; ++s) {
    int i = s * 256 + tid;
    int row = i >> 2, cb = (i & 3) * 8;
    gA[s] = H + ((size_t)e * CAP + m0 + row) * DFF + kbase + cb;
    gB[s] = w2t + ((size_t)e * DMODEL + n0 + row) * DFF + kbase + cb;
    int wb = (s * 256 + wv * 64) * 8;
    lA[s] = As + wb;
    lB[s] = Bs + wb;
  }

  f32x4 zero = {0.f, 0.f, 0.f, 0.f};
  f32x4 acc[4][4];
#pragma unroll
  for (int mi = 0; mi < 4; ++mi)
#pragma unroll
    for (int ni = 0; ni < 4; ++ni) acc[mi][ni] = zero;

  int wm = (wv >> 1) * 64, wn = (wv & 1) * 64;
  int fr = lane & 15, quad = lane >> 4;
  const unsigned short* pa = As + (wm + fr) * 32 + quad * 8;
  const unsigned short* pb = Bs + (wn + fr) * 32 + quad * 8;

  for (int k0 = 0; k0 < DFF / 2; k0 += 32) {
#pragma unroll
    for (int s = 0; s < 2; ++s) {
      load_lds16(gA[s] + k0, lA[s]);
      load_lds16(gB[s] + k0, lB[s]);
    }
    __syncthreads();
    bf16x8 av[4], bv[4];
#pragma unroll
    for (int mi = 0; mi < 4; ++mi) av[mi] = *(const bf16x8*)(pa + mi * 16 * 32);
#pragma unroll
    for (int ni = 0; ni < 4; ++ni) bv[ni] = *(const bf16x8*)(pb + ni * 16 * 32);
#pragma unroll
    for (int mi = 0; mi < 4; ++mi)
#pragma unroll
      for (int ni = 0; ni < 4; ++ni)
        acc[mi][ni] = __builtin_amdgcn_mfma_f32_16x16x32_bf16(av[mi], bv[ni], acc[mi][ni], 0, 0, 0);
    __syncthreads();
  }

  float bs[4];
  int cols[4];
#pragma unroll
  for (int ni = 0; ni < 4; ++ni) {
    cols[ni] = n0 + wn + ni * 16 + fr;
    bs[ni] = (ks == 0) ? b2[e * DMODEL + cols[ni]] : 0.0f;   // bias only on slice 0
  }
#pragma unroll
  for (int mi = 0; mi < 4; ++mi) {
    int mbase = m0 + wm + mi * 16 + quad * 4;
#pragma unroll
    for (int rr = 0; rr < 4; ++rr) {
      int mrow = mbase + rr;
      int tok = etok[e * CAP + mrow];
      float g = egate[e * CAP + mrow];
      if (g != 0.f) {
        float* orow = out + (size_t)tok * DMODEL;
#pragma unroll
        for (int ni = 0; ni < 4; ++ni)
          atomicAdd(orow + cols[ni], g * (acc[mi][ni][rr] + bs[ni]));
      }
    }
  }
}

extern "C" void kernel_launch(void* const* d_in, const int* in_sizes, int n_in,
                              void* d_out, int out_size, void* d_ws, size_t ws_size,
                              hipStream_t stream) {
  (void)in_sizes; (void)n_in; (void)ws_size;
  const float* x  = (const float*)d_in[0];
  const float* rw = (const float*)d_in[1];
  const float* w1 = (const float*)d_in[2];
  const float* b1 = (const float*)d_in[3];
  const float* w2 = (const float*)d_in[4];
  const float* b2 = (const float*)d_in[5];
  float* out = (float*)d_out;

  char* ws = (char*)d_ws;
  const size_t XB_BYTES = (size_t)T_TOK * DMODEL * 2;          // 16 MiB
  const size_t WT_BYTES = (size_t)NEXP * DFF * DMODEL * 2;     // 64 MiB (w1t, then w2t)
  const size_t H_BYTES  = (size_t)NEXP * CAP * DFF * 2;        // 64 MiB
  unsigned short* xb = (unsigned short*)ws;
  unsigned short* wT = (unsigned short*)(ws + XB_BYTES);
  unsigned short* Hb = (unsigned short*)(ws + XB_BYTES + WT_BYTES);
  char* small = ws + XB_BYTES + WT_BYTES + H_BYTES;
  int*   etok  = (int*)small;
  float* egate = (float*)(small + NEXP * CAP * 4);
  int*   tkidx = (int*)(small + 2 * NEXP * CAP * 4);
  float* tkw   = (float*)(small + 2 * NEXP * CAP * 4 + T_TOK * 2 * 4);

  hipMemsetAsync(d_out, 0, (size_t)out_size * sizeof(float), stream);
  k_router<<<T_TOK / 4, 256, 0, stream>>>(x, rw, xb, tkidx, tkw);
  k_scan<<<1, 1024, 0, stream>>>(tkidx, tkw, etok, egate,
                                 (float*)d_out + (size_t)T_TOK * DMODEL);
  k_transpose_cvt<<<dim3(DFF / 64, DMODEL / 64, NEXP), 256, 0, stream>>>(w1, wT, DMODEL, DFF);
  k_gemm1<<<NEXP * 256, 256, 0, stream>>>(xb, wT, b1, etok, Hb);
  k_transpose_cvt<<<dim3(DMODEL / 64, DFF / 64, NEXP), 256, 0, stream>>>(w2, wT, DFF, DMODEL);
  k_gemm2<<<NEXP * 128, 256, 0, stream>>>(Hb, wT, b2, etok, egate, out);
}

// Round 4
// 558.506 us; speedup vs baseline: 1.0929x; 1.0929x over previous
//
#include <hip/hip_runtime.h>
#include <hip/hip_bf16.h>

#define T_TOK 8192
#define DMODEL 1024
#define DFF 4096
#define NEXP 8
#define CAP 1024

typedef __attribute__((ext_vector_type(8))) __bf16 bf16x8;
typedef __attribute__((ext_vector_type(4))) float f32x4;

__device__ __forceinline__ unsigned short f2bf(float f) {
  union { float f; unsigned int u; } v;
  v.f = f;
  return (unsigned short)((v.u + 0x7fffu + ((v.u >> 16) & 1u)) >> 16);
}

__device__ __forceinline__ float bfbits2f(unsigned int lo16) {
  union { unsigned int u; float f; } v; v.u = lo16 << 16; return v.f;
}

// A&S 7.1.26 erf (|err| <= 1.5e-7). gelu = 0.5 v (1+erf(v/sqrt2))
__device__ __forceinline__ float fast_gelu(float v) {
  float x = fabsf(v) * 0.70710678118654752440f;
  float t = __builtin_amdgcn_rcpf(1.0f + 0.3275911f * x);
  float poly = t * (0.254829592f + t * (-0.284496736f + t * (1.421413741f +
               t * (-1.453152027f + t * 1.061405429f))));
  float er = 1.0f - poly * __expf(-x * x);
  float s = (v >= 0.0f) ? er : -er;
  return 0.5f * v * (1.0f + s);
}

__device__ __forceinline__ void load_lds16(const unsigned short* g, unsigned short* l) {
  __builtin_amdgcn_global_load_lds((const __attribute__((address_space(1))) void*)g,
                                   (__attribute__((address_space(3))) void*)l,
                                   16, 0, 0);
}

// ---------------- router (fused x->bf16 convert + tinv init): one wave per token ----------------
__global__ void k_router(const float* __restrict__ x, const float* __restrict__ rw,
                         unsigned short* __restrict__ xb,
                         int* __restrict__ tk_idx, float* __restrict__ tk_w,
                         int* __restrict__ tinv) {
  if (threadIdx.x < 8) tinv[blockIdx.x * 8 + threadIdx.x] = -1;  // tokens 4b..4b+3, K=2
  int wv = threadIdx.x >> 6, lane = threadIdx.x & 63;
  int t = blockIdx.x * 4 + wv;
  const float4* xr = (const float4*)(x + (size_t)t * DMODEL);
  uint2* xbw = (uint2*)(xb + (size_t)t * DMODEL);
  float acc[NEXP];
#pragma unroll
  for (int e = 0; e < NEXP; ++e) acc[e] = 0.f;
#pragma unroll
  for (int j = 0; j < DMODEL / 256; ++j) {
    float4 v = xr[j * 64 + lane];
#pragma unroll
    for (int e = 0; e < NEXP; ++e) {
      float4 w = ((const float4*)(rw + e * DMODEL))[j * 64 + lane];
      acc[e] += v.x * w.x + v.y * w.y + v.z * w.z + v.w * w.w;
    }
    uint2 p;
    p.x = (unsigned int)f2bf(v.x) | ((unsigned int)f2bf(v.y) << 16);
    p.y = (unsigned int)f2bf(v.z) | ((unsigned int)f2bf(v.w) << 16);
    xbw[j * 64 + lane] = p;
  }
#pragma unroll
  for (int e = 0; e < NEXP; ++e)
    for (int off = 32; off; off >>= 1) acc[e] += __shfl_xor(acc[e], off);
  if (lane == 0) {
    int i0 = 0;
    for (int e = 1; e < NEXP; ++e) if (acc[e] > acc[i0]) i0 = e;
    int i1 = (i0 == 0) ? 1 : 0;
    for (int e = 0; e < NEXP; ++e) if (e != i0 && acc[e] > acc[i1]) i1 = e;
    float ex = expf(acc[i1] - acc[i0]);  // <= 1
    float w0 = 1.f / (1.f + ex);
    float w1 = ex / (1.f + ex);
    tk_idx[2 * t] = i0; tk_idx[2 * t + 1] = i1;
    tk_w[2 * t] = w0;  tk_w[2 * t + 1] = w1;
  }
}

// ---------------- fp32 [E][Kd][Nd] -> bf16 [E][Nd][Kd] ----------------
__global__ void k_transpose_cvt(const float* __restrict__ src, unsigned short* __restrict__ dst,
                                int Kd, int Nd) {
  __shared__ unsigned short tile[64][73];
  int e = blockIdx.z;
  size_t k0 = (size_t)blockIdx.y * 64, n0 = (size_t)blockIdx.x * 64;
  int tid = threadIdx.x;
  const float* sb = src + (size_t)e * Kd * Nd;
  int r = tid >> 4, cg = (tid & 15) * 4;
  for (int rr = 0; rr < 4; ++rr) {
    int row = r + rr * 16;
    float4 v = *(const float4*)(sb + (k0 + row) * Nd + n0 + cg);
    tile[row][cg + 0] = f2bf(v.x);
    tile[row][cg + 1] = f2bf(v.y);
    tile[row][cg + 2] = f2bf(v.z);
    tile[row][cg + 3] = f2bf(v.w);
  }
  __syncthreads();
  unsigned short* db = dst + (size_t)e * Nd * Kd;
  int rn = tid >> 3, kg = (tid & 7) * 8;
  for (int rr = 0; rr < 2; ++rr) {
    int nrow = rn + rr * 32;
    union { unsigned short h[8]; uint4 v; } o;
#pragma unroll
    for (int j = 0; j < 8; ++j) o.h[j] = tile[kg + j][nrow];
    *(uint4*)(db + (n0 + nrow) * Kd + k0 + kg) = o.v;
  }
}

// ---------------- capacity scan: one block per expert, token order ----------------
__global__ void k_scan(const int* __restrict__ tk_idx, const float* __restrict__ tk_w,
                       int* __restrict__ etok, float* __restrict__ egate,
                       int* __restrict__ tinv, int* __restrict__ counts) {
  __shared__ int wavecnt[16], waveoff[16];
  __shared__ int soff;
  int e = blockIdx.x;
  int tid = threadIdx.x, lane = tid & 63, wv = tid >> 6;
  for (int i = tid; i < CAP; i += 1024) etok[e * CAP + i] = 0;
  if (tid == 0) soff = 0;
  __syncthreads();
  unsigned long long lt = (1ULL << lane) - 1ULL;
  for (int c = 0; c < T_TOK / 1024; ++c) {
    int t = c * 1024 + tid;
    int e0 = tk_idx[2 * t], e1 = tk_idx[2 * t + 1];
    bool is0 = (e0 == e), is1 = (e1 == e);
    bool mine = is0 || is1;
    unsigned long long bal = __ballot(mine);
    int pos = __popcll(bal & lt);
    if (lane == 0) wavecnt[wv] = __popcll(bal);
    __syncthreads();
    if (tid == 0) {
      int s = soff;
      for (int w = 0; w < 16; ++w) { waveoff[w] = s; s += wavecnt[w]; }
      soff = s;
    }
    __syncthreads();
    if (mine) {
      int r = waveoff[wv] + pos;
      if (r < CAP) {
        etok[e * CAP + r] = t;
        egate[e * CAP + r] = is0 ? tk_w[2 * t] : tk_w[2 * t + 1];
        tinv[2 * t + (is1 ? 1 : 0)] = e * CAP + r;
      }
    }
    __syncthreads();
  }
  if (tid == 0) counts[e] = soff;  // uncapped total (for lb_loss)
}

// ---------------- GEMM1: H[e] = gelu(X[etok[e]] @ w1[e] + b1[e]) -> bf16 ----------------
// Swapped-operand MFMA (acc holds D^T). Epilogue reuses the 16 KB k-loop LDS.
__global__ __launch_bounds__(256) void k_gemm1(
    const unsigned short* __restrict__ xb, const unsigned short* __restrict__ w1t,
    const float* __restrict__ b1, const int* __restrict__ etok,
    unsigned short* __restrict__ H) {
  __shared__ __align__(16) unsigned short smem[8192];
  unsigned short* As = smem;
  unsigned short* Bs = smem + 4096;
  int tid = threadIdx.x;
  int lane = tid & 63, wv = tid >> 6;
  int bid = blockIdx.x;
  int e = bid >> 8;
  int b = bid & 255;
  int nl = b & 7, m = (b >> 3) & 7, nh = b >> 6;
  int m0 = m * 128, n0 = (nh * 8 + nl) * 128;  // bid%8 = n-tile => XCD shares B

  const unsigned short* gA[2];
  const unsigned short* gB[2];
  unsigned short* lA[2];
  unsigned short* lB[2];
#pragma unroll
  for (int s = 0; s < 2; ++s) {
    int i = s * 256 + tid;
    int row = i >> 2, cb = (i & 3) * 8;
    int tok = etok[e * CAP + m0 + row];
    gA[s] = xb + (size_t)tok * DMODEL + cb;
    gB[s] = w1t + ((size_t)e * DFF + n0 + row) * DMODEL + cb;
    int wb = (s * 256 + wv * 64) * 8;
    lA[s] = As + wb;
    lB[s] = Bs + wb;
  }

  f32x4 zero = {0.f, 0.f, 0.f, 0.f};
  f32x4 acc[4][4];
#pragma unroll
  for (int mi = 0; mi < 4; ++mi)
#pragma unroll
    for (int ni = 0; ni < 4; ++ni) acc[mi][ni] = zero;

  int wm = (wv >> 1) * 64, wn = (wv & 1) * 64;
  int fr = lane & 15, quad = lane >> 4;
  const unsigned short* pa = As + (wm + fr) * 32 + quad * 8;
  const unsigned short* pb = Bs + (wn + fr) * 32 + quad * 8;

  for (int k0 = 0; k0 < DMODEL; k0 += 32) {
#pragma unroll
    for (int s = 0; s < 2; ++s) {
      load_lds16(gA[s] + k0, lA[s]);
      load_lds16(gB[s] + k0, lB[s]);
    }
    __syncthreads();
    bf16x8 av[4], bv[4];
#pragma unroll
    for (int mi = 0; mi < 4; ++mi) av[mi] = *(const bf16x8*)(pa + mi * 16 * 32);
#pragma unroll
    for (int ni = 0; ni < 4; ++ni) bv[ni] = *(const bf16x8*)(pb + ni * 16 * 32);
#pragma unroll
    for (int mi = 0; mi < 4; ++mi)
#pragma unroll
      for (int ni = 0; ni < 4; ++ni)
        acc[mi][ni] = __builtin_amdgcn_mfma_f32_16x16x32_bf16(bv[ni], av[mi], acc[mi][ni], 0, 0, 0);
    __syncthreads();
  }

  unsigned short* EP = smem + wv * 1536;
#pragma unroll
  for (int ni = 0; ni < 4; ++ni) {
    float4 b4 = *(const float4*)(b1 + e * DFF + n0 + wn + ni * 16 + quad * 4);
#pragma unroll
    for (int mi = 0; mi < 4; ++mi) {
      float v0 = fast_gelu(acc[mi][ni][0] + b4.x);
      float v1 = fast_gelu(acc[mi][ni][1] + b4.y);
      float v2 = fast_gelu(acc[mi][ni][2] + b4.z);
      float v3 = fast_gelu(acc[mi][ni][3] + b4.w);
      uint2 p;
      p.x = (unsigned int)f2bf(v0) | ((unsigned int)f2bf(v1) << 16);
      p.y = (unsigned int)f2bf(v2) | ((unsigned int)f2bf(v3) << 16);
      *(uint2*)(EP + (mi * 16 + fr) * 24 + quad * 4) = p;
    }
#pragma unroll
    for (int t = 0; t < 2; ++t) {
      int row = t * 32 + (lane >> 1), chunk = lane & 1;
      uint4 v = *(const uint4*)(EP + row * 24 + chunk * 8);
      *(uint4*)(H + ((size_t)e * CAP + m0 + wm + row) * DFF + n0 + wn + ni * 16 + chunk * 8) = v;
    }
  }
}

// ---------------- GEMM2: Y[e][slot] = H[e][slot] @ w2[e] + b2[e] -> bf16 (no atomics) ----------
__global__ __launch_bounds__(256) void k_gemm2(
    const unsigned short* __restrict__ H, const unsigned short* __restrict__ w2t,
    const float* __restrict__ b2, unsigned short* __restrict__ Y) {
  __shared__ __align__(16) unsigned short smem[8192];
  unsigned short* As = smem;
  unsigned short* Bs = smem + 4096;
  int tid = threadIdx.x;
  int lane = tid & 63, wv = tid >> 6;
  int bid = blockIdx.x;
  int e = bid >> 6;
  int m0 = ((bid >> 3) & 7) * 128;
  int n0 = (bid & 7) * 128;  // bid%8 = n-tile => XCD shares w2 tile

  const unsigned short* gA[2];
  const unsigned short* gB[2];
  unsigned short* lA[2];
  unsigned short* lB[2];
#pragma unroll
  for (int s = 0; s < 2; ++s) {
    int i = s * 256 + tid;
    int row = i >> 2, cb = (i & 3) * 8;
    gA[s] = H + ((size_t)e * CAP + m0 + row) * DFF + cb;
    gB[s] = w2t + ((size_t)e * DMODEL + n0 + row) * DFF + cb;
    int wb = (s * 256 + wv * 64) * 8;
    lA[s] = As + wb;
    lB[s] = Bs + wb;
  }

  f32x4 zero = {0.f, 0.f, 0.f, 0.f};
  f32x4 acc[4][4];
#pragma unroll
  for (int mi = 0; mi < 4; ++mi)
#pragma unroll
    for (int ni = 0; ni < 4; ++ni) acc[mi][ni] = zero;

  int wm = (wv >> 1) * 64, wn = (wv & 1) * 64;
  int fr = lane & 15, quad = lane >> 4;
  const unsigned short* pa = As + (wm + fr) * 32 + quad * 8;
  const unsigned short* pb = Bs + (wn + fr) * 32 + quad * 8;

  for (int k0 = 0; k0 < DFF; k0 += 32) {
#pragma unroll
    for (int s = 0; s < 2; ++s) {
      load_lds16(gA[s] + k0, lA[s]);
      load_lds16(gB[s] + k0, lB[s]);
    }
    __syncthreads();
    bf16x8 av[4], bv[4];
#pragma unroll
    for (int mi = 0; mi < 4; ++mi) av[mi] = *(const bf16x8*)(pa + mi * 16 * 32);
#pragma unroll
    for (int ni = 0; ni < 4; ++ni) bv[ni] = *(const bf16x8*)(pb + ni * 16 * 32);
#pragma unroll
    for (int mi = 0; mi < 4; ++mi)
#pragma unroll
      for (int ni = 0; ni < 4; ++ni)
        acc[mi][ni] = __builtin_amdgcn_mfma_f32_16x16x32_bf16(bv[ni], av[mi], acc[mi][ni], 0, 0, 0);
    __syncthreads();
  }

  unsigned short* EP = smem + wv * 1536;
#pragma unroll
  for (int ni = 0; ni < 4; ++ni) {
    float4 b4 = *(const float4*)(b2 + e * DMODEL + n0 + wn + ni * 16 + quad * 4);
#pragma unroll
    for (int mi = 0; mi < 4; ++mi) {
      uint2 p;
      p.x = (unsigned int)f2bf(acc[mi][ni][0] + b4.x) |
            ((unsigned int)f2bf(acc[mi][ni][1] + b4.y) << 16);
      p.y = (unsigned int)f2bf(acc[mi][ni][2] + b4.z) |
            ((unsigned int)f2bf(acc[mi][ni][3] + b4.w) << 16);
      *(uint2*)(EP + (mi * 16 + fr) * 24 + quad * 4) = p;
    }
#pragma unroll
    for (int t = 0; t < 2; ++t) {
      int row = t * 32 + (lane >> 1), chunk = lane & 1;
      uint4 v = *(const uint4*)(EP + row * 24 + chunk * 8);
      *(uint4*)(Y + ((size_t)e * CAP + m0 + wm + row) * DMODEL + n0 + wn + ni * 16 + chunk * 8) = v;
    }
  }
}

// ---------------- combine: out[t] = sum_k gate * Y[slot_k]; also writes zeros + loss ---------
__global__ void k_combine(const unsigned short* __restrict__ Y,
                          const float* __restrict__ egate,
                          const int* __restrict__ tinv,
                          const int* __restrict__ counts,
                          float* __restrict__ out, float* __restrict__ loss_out) {
  int t = blockIdx.x, tid = threadIdx.x;
  int s0 = tinv[2 * t], s1 = tinv[2 * t + 1];
  int d0 = tid * 4;
  float a0 = 0.f, a1 = 0.f, a2 = 0.f, a3 = 0.f;
  if (s0 >= 0) {
    float g = egate[s0];
    uint2 v = *(const uint2*)(Y + (size_t)s0 * DMODEL + d0);
    a0 += g * bfbits2f(v.x & 0xffff); a1 += g * bfbits2f(v.x >> 16);
    a2 += g * bfbits2f(v.y & 0xffff); a3 += g * bfbits2f(v.y >> 16);
  }
  if (s1 >= 0) {
    float g = egate[s1];
    uint2 v = *(const uint2*)(Y + (size_t)s1 * DMODEL + d0);
    a0 += g * bfbits2f(v.x & 0xffff); a1 += g * bfbits2f(v.x >> 16);
    a2 += g * bfbits2f(v.y & 0xffff); a3 += g * bfbits2f(v.y >> 16);
  }
  float4 o = {a0, a1, a2, a3};
  *(float4*)(out + (size_t)t * DMODEL + d0) = o;
  if (t == 0 && tid == 0) {
    float loss = 0.f;
    for (int e = 0; e < NEXP; ++e) {
      float d = (float)counts[e] - 2048.0f;
      loss += d * d;
    }
    loss_out[0] = loss / (8192.0f * 8192.0f);
  }
}

extern "C" void kernel_launch(void* const* d_in, const int* in_sizes, int n_in,
                              void* d_out, int out_size, void* d_ws, size_t ws_size,
                              hipStream_t stream) {
  (void)in_sizes; (void)n_in; (void)ws_size; (void)out_size;
  const float* x  = (const float*)d_in[0];
  const float* rw = (const float*)d_in[1];
  const float* w1 = (const float*)d_in[2];
  const float* b1 = (const float*)d_in[3];
  const float* w2 = (const float*)d_in[4];
  const float* b2 = (const float*)d_in[5];
  float* out = (float*)d_out;

  char* ws = (char*)d_ws;
  const size_t XB_BYTES = (size_t)T_TOK * DMODEL * 2;          // 16 MiB (xb; Y aliases after gemm1)
  const size_t WT_BYTES = (size_t)NEXP * DFF * DMODEL * 2;     // 64 MiB (w1t, then w2t)
  const size_t H_BYTES  = (size_t)NEXP * CAP * DFF * 2;        // 64 MiB
  unsigned short* xb = (unsigned short*)ws;
  unsigned short* Yb = xb;                                      // alias: xb dead after gemm1
  unsigned short* wT = (unsigned short*)(ws + XB_BYTES);
  unsigned short* Hb = (unsigned short*)(ws + XB_BYTES + WT_BYTES);
  char* small = ws + XB_BYTES + WT_BYTES + H_BYTES;
  int*   etok   = (int*)small;                                  // 32 KB
  float* egate  = (float*)(small + NEXP * CAP * 4);             // 32 KB
  int*   tkidx  = (int*)(small + 2 * NEXP * CAP * 4);           // 64 KB
  float* tkw    = (float*)(small + 2 * NEXP * CAP * 4 + T_TOK * 2 * 4);  // 64 KB
  int*   tinv   = (int*)(small + 2 * NEXP * CAP * 4 + 2 * T_TOK * 2 * 4);// 64 KB
  int*   counts = (int*)(small + 2 * NEXP * CAP * 4 + 3 * T_TOK * 2 * 4);// 32 B

  k_router<<<T_TOK / 4, 256, 0, stream>>>(x, rw, xb, tkidx, tkw, tinv);
  k_scan<<<NEXP, 1024, 0, stream>>>(tkidx, tkw, etok, egate, tinv, counts);
  k_transpose_cvt<<<dim3(DFF / 64, DMODEL / 64, NEXP), 256, 0, stream>>>(w1, wT, DMODEL, DFF);
  k_gemm1<<<NEXP * 256, 256, 0, stream>>>(xb, wT, b1, etok, Hb);
  k_transpose_cvt<<<dim3(DMODEL / 64, DFF / 64, NEXP), 256, 0, stream>>>(w2, wT, DFF, DMODEL);
  k_gemm2<<<NEXP * 64, 256, 0, stream>>>(Hb, wT, b2, Yb);
  k_combine<<<T_TOK, 256, 0, stream>>>(Yb, egate, tinv, counts, out,
                                       out + (size_t)T_TOK * DMODEL);
}